// Round 9
// baseline (2783.134 us; speedup 1.0000x reference)
//
#include <hip/hip_runtime.h>
#include <cstdint>
#include <cstddef>

#define BSZ 32768
#define WN 7
#define WF 560
#define K1P 576
#define EPS 1e-5f

typedef __attribute__((ext_vector_type(8))) short bf16x8;
typedef __attribute__((ext_vector_type(4))) float f32x4;

__device__ __forceinline__ float b2f(short s) {
  union { float f; unsigned u; } x; x.u = ((unsigned)(unsigned short)s) << 16; return x.f;
}
__device__ __forceinline__ short f2b(float f) {
  union { float f; unsigned u; } x; x.f = f;
  unsigned r = x.u + 0x7fffu + ((x.u >> 16) & 1u);
  return (short)(r >> 16);
}
__device__ __forceinline__ float sigf(float x) { return 1.0f / (1.0f + __expf(-x)); }
// overflow-safe fast tanh via __expf
__device__ __forceinline__ float ftanh(float x) {
  float t = __expf(-2.0f * fabsf(x));
  float r = (1.0f - t) / (1.0f + t);
  return copysignf(r, x);
}

__device__ __forceinline__ void async_copy16(const short* g, short* l) {
  __builtin_amdgcn_global_load_lds((const __attribute__((address_space(1))) unsigned*)g,
                                   (__attribute__((address_space(3))) unsigned*)l, 16, 0, 0);
}

// ---------------- weight folding (run every call; cheap) ----------------

__global__ void fold_small_k(const float* __restrict__ dec_w, const float* __restrict__ dec_b,
                             const float* __restrict__ dec_g, const float* __restrict__ dec_bt,
                             const float* __restrict__ dec_m, const float* __restrict__ dec_v,
                             const float* __restrict__ ea1_w, const float* __restrict__ ea1_b,
                             const float* __restrict__ ea1_g, const float* __restrict__ ea1_bt,
                             const float* __restrict__ ea1_m, const float* __restrict__ ea1_v,
                             float* __restrict__ decwf, float* __restrict__ decb8,
                             float* __restrict__ ea1f)
{
  int t = blockIdx.x * 256 + threadIdx.x;
  if (t < 7 * 512) {
    int w = t >> 9;
    float s = dec_g[w] * rsqrtf(dec_v[w] + EPS);
    decwf[t] = dec_w[t] * s;
  }
  if (t < 8) {
    if (t < 7) {
      float s = dec_g[t] * rsqrtf(dec_v[t] + EPS);
      decb8[t] = (dec_b[t] - dec_m[t]) * s + dec_bt[t];
    } else decb8[t] = 0.0f;
  }
  if (t < 512) {
    float s = ea1_g[t] * rsqrtf(ea1_v[t] + EPS);
    #pragma unroll
    for (int w = 0; w < 7; ++w) ea1f[t * 8 + w] = ea1_w[t * 7 + w] * s;
    ea1f[t * 8 + 7] = (ea1_b[t] - ea1_m[t]) * s + ea1_bt[t];
  }
}

__global__ void fold_ei1_k(const float* __restrict__ w, const float* __restrict__ b,
                           const float* __restrict__ g, const float* __restrict__ bt,
                           const float* __restrict__ m, const float* __restrict__ v,
                           short* __restrict__ ei1f, float* __restrict__ bias1)
{
  int idx = blockIdx.x * 256 + threadIdx.x;   // 512*576
  int n = idx / K1P, k = idx % K1P;
  float s = g[n] * rsqrtf(v[n] + EPS);
  ei1f[idx] = (k < WF) ? f2b(w[n * WF + k] * s) : (short)0;
  if (k == 0) bias1[n] = (b[n] - m[n]) * s + bt[n];
}

__global__ void fold_w2_k(const float* __restrict__ wi, const float* __restrict__ bi,
                          const float* __restrict__ gi, const float* __restrict__ bti,
                          const float* __restrict__ mi, const float* __restrict__ vi,
                          const float* __restrict__ wa, const float* __restrict__ ba,
                          const float* __restrict__ ga, const float* __restrict__ bta,
                          const float* __restrict__ ma, const float* __restrict__ va,
                          short* __restrict__ W2, float* __restrict__ bias2)
{
  int idx = blockIdx.x * 256 + threadIdx.x;   // 512*1024
  int n = idx >> 10, k = idx & 1023;
  float si = gi[n] * rsqrtf(vi[n] + EPS);
  float sa = ga[n] * rsqrtf(va[n] + EPS);
  float val = (k < 512) ? wi[n * 512 + k] * si : wa[n * 512 + (k - 512)] * sa;
  W2[idx] = f2b(val);
  if (k == 0)
    bias2[n] = (bi[n] - mi[n]) * si + bti[n] + (ba[n] - ma[n]) * sa + bta[n];
}

// Reordered gate weights: new column c = (u>>4)*64 + g*16 + (u&15)
// so that in the MFMA epilogue, n-fragment index (mod 4) == gate, lane&15 == unit offset.
__global__ void fold_wg_k(const float* __restrict__ w_ih, const float* __restrict__ w_hh,
                          const float* __restrict__ b_ih, const float* __restrict__ b_hh,
                          short* __restrict__ Wg, float* __restrict__ biasg)
{
  int idx = blockIdx.x * 256 + threadIdx.x;   // 2048*1024
  int c = idx >> 10, k = idx & 1023;
  int g = (c >> 4) & 3;
  int u = (c >> 6) * 16 + (c & 15);
  int r = g * 512 + u;
  float val = (k < 512) ? w_ih[r * 512 + k] : w_hh[r * 512 + (k - 512)];
  Wg[idx] = f2b(val);
  if (k == 0) biasg[c] = b_ih[r] + b_hh[r];
}

// ---------------- fused attention / LN / a1 / feature-scale ----------------
__global__ __launch_bounds__(512)
void attln_k(const float* __restrict__ hbuf, const float* __restrict__ cbuf,
             const float* __restrict__ decwf, const float* __restrict__ decb8,
             const float* __restrict__ ea1f,
             const float* __restrict__ ln_g, const float* __restrict__ ln_b,
             const float* __restrict__ feat,
             short* __restrict__ ghA, short* __restrict__ c_ln,
             short* __restrict__ xa, short* __restrict__ ai, int init)
{
  const int lane = threadIdx.x & 63;
  const int b = blockIdx.x * 8 + (threadIdx.x >> 6);
  float av[WN];
  if (init) {
    const float c7 = 1.0f / 7.0f;
    #pragma unroll
    for (int w = 0; w < WN; ++w) av[w] = c7;
    int4 z = make_int4(0, 0, 0, 0);
    *(int4*)&ghA[b * 1024 + 512 + lane * 8] = z;
    *(int4*)&c_ln[b * 512 + lane * 8] = z;
  } else {
    float hl[8];
    const float* hp = hbuf + (size_t)b * 512 + lane * 8;
    *(float4*)&hl[0] = *(const float4*)hp;
    *(float4*)&hl[4] = *(const float4*)(hp + 4);
    float s = 0.f, s2 = 0.f;
    #pragma unroll
    for (int e = 0; e < 8; ++e) { s += hl[e]; s2 += hl[e] * hl[e]; }
    float p[WN];
    #pragma unroll
    for (int w = 0; w < WN; ++w) {
      const float* dw = decwf + w * 512 + lane * 8;
      float4 w0 = *(const float4*)dw, w1 = *(const float4*)(dw + 4);
      p[w] = hl[0] * w0.x + hl[1] * w0.y + hl[2] * w0.z + hl[3] * w0.w
           + hl[4] * w1.x + hl[5] * w1.y + hl[6] * w1.z + hl[7] * w1.w;
    }
    #pragma unroll
    for (int o = 32; o > 0; o >>= 1) {
      s  += __shfl_xor(s, o);
      s2 += __shfl_xor(s2, o);
      #pragma unroll
      for (int w = 0; w < WN; ++w) p[w] += __shfl_xor(p[w], o);
    }
    float mu = s * (1.0f / 512.0f);
    float var = s2 * (1.0f / 512.0f) - mu * mu;
    float rstd = rsqrtf(var + EPS);
    float ssum = 0.f;
    #pragma unroll
    for (int w = 0; w < WN; ++w) { float sg = sigf(p[w] + decb8[w]); av[w] = sg; ssum += sg; }
    float inv = 1.0f / ssum;
    #pragma unroll
    for (int w = 0; w < WN; ++w) av[w] *= inv;
    short o8[8];
    #pragma unroll
    for (int e = 0; e < 8; ++e) {
      int i = lane * 8 + e;
      o8[e] = f2b((hl[e] - mu) * rstd * ln_g[i] + ln_b[i]);
    }
    *(int4*)&ghA[b * 1024 + 512 + lane * 8] = *(int4*)o8;
    float cl[8];
    const float* cp = cbuf + (size_t)b * 512 + lane * 8;
    *(float4*)&cl[0] = *(const float4*)cp;
    *(float4*)&cl[4] = *(const float4*)(cp + 4);
    float cs = 0.f, cs2 = 0.f;
    #pragma unroll
    for (int e = 0; e < 8; ++e) { cs += cl[e]; cs2 += cl[e] * cl[e]; }
    #pragma unroll
    for (int o = 32; o > 0; o >>= 1) {
      cs  += __shfl_xor(cs, o);
      cs2 += __shfl_xor(cs2, o);
    }
    float cmu = cs * (1.0f / 512.0f);
    float cvar = cs2 * (1.0f / 512.0f) - cmu * cmu;
    float crstd = rsqrtf(cvar + EPS);
    #pragma unroll
    for (int e = 0; e < 8; ++e) {
      int i = lane * 8 + e;
      o8[e] = f2b((cl[e] - cmu) * crstd * ln_g[i] + ln_b[i]);
    }
    *(int4*)&c_ln[b * 512 + lane * 8] = *(int4*)o8;
  }
  short a8[8];
  #pragma unroll
  for (int e = 0; e < 8; ++e) {
    int n = lane * 8 + e;
    const float* wr = ea1f + n * 8;
    float4 w0 = *(const float4*)wr, w1 = *(const float4*)(wr + 4);
    float v = w1.w
            + av[0] * w0.x + av[1] * w0.y + av[2] * w0.z + av[3] * w0.w
            + av[4] * w1.x + av[5] * w1.y + av[6] * w1.z;
    a8[e] = f2b(fmaxf(v, 0.0f));
  }
  *(int4*)&xa[b * 1024 + 512 + lane * 8] = *(int4*)a8;
  const float* fr = feat + (size_t)b * WF;
  short* air = ai + (size_t)b * K1P;
  #pragma unroll
  for (int rr = 0; rr < 2; ++rr) {
    int c8 = lane + rr * 64;
    if (c8 < 72) {
      int k = c8 * 8;
      short s8[8];
      if (k < WF) {
        int window = c8 / 10;
        float a = av[0];
        #pragma unroll
        for (int w = 1; w < WN; ++w) a = (window == w) ? av[w] : a;
        float4 f0 = *(const float4*)(fr + k);
        float4 f1 = *(const float4*)(fr + k + 4);
        s8[0] = f2b(f0.x * a); s8[1] = f2b(f0.y * a); s8[2] = f2b(f0.z * a); s8[3] = f2b(f0.w * a);
        s8[4] = f2b(f1.x * a); s8[5] = f2b(f1.y * a); s8[6] = f2b(f1.z * a); s8[7] = f2b(f1.w * a);
      } else {
        #pragma unroll
        for (int e = 0; e < 8; ++e) s8[e] = 0;
      }
      *(int4*)&air[k] = *(int4*)s8;
    }
  }
}

// ---- shared 128x128 MFMA core with conflict-free LDS (both-sides XOR swizzle) ----
#define STAGE128(SRC, LD, K0, S) do {                                          \
    _Pragma("unroll")                                                          \
    for (int r_ = 0; r_ < 4; ++r_) {                                           \
      int idx_ = r_ * 256 + t;                                                 \
      int row_ = idx_ >> 3, dcol_ = (idx_ & 7) * 8;                            \
      int scol_ = dcol_ ^ ((row_ & 7) << 3);                                   \
      async_copy16(SRC + (size_t)row_ * (LD) + (K0) + scol_, &S[idx_ * 8]);    \
    }                                                                          \
  } while (0)

#define READ_FRAG(S, ROW, KS) \
  (*(const bf16x8*)&S[(ROW) * 64 + (((KS)) ^ (((ROW) & 7) << 3))])

// ---------------- encoder GEMM: C = ReLU(A @ W^T + bias), 128x128 tile ----------------
__global__ __launch_bounds__(256)
void gemm_bt_k(const short* __restrict__ A, int lda,
               const short* __restrict__ Wt, int K,
               const float* __restrict__ bias,
               short* __restrict__ C, int ldc)
{
  const int bswz = blockIdx.x;
  const int xcd = bswz & 7, slot = bswz >> 3;
  const int m0 = (xcd + 8 * (slot >> 2)) * 128;
  const int n0 = (slot & 3) * 128;
  __shared__ short sA[128 * 64];
  __shared__ short sB[128 * 64];
  const int t = threadIdx.x;
  const int wv = t >> 6, lane = t & 63;
  const int wm = (wv & 1) * 64, wn = (wv >> 1) * 64;
  const int lr = lane & 15, lk = (lane >> 4) * 8;

  f32x4 acc[4][4] = {};
  const short* Ab = A + (size_t)m0 * lda;
  const short* Wb = Wt + (size_t)n0 * K;

  for (int k0 = 0; k0 < K; k0 += 64) {
    STAGE128(Ab, lda, k0, sA);
    STAGE128(Wb, K, k0, sB);
    __syncthreads();
    #pragma unroll
    for (int ks = 0; ks < 64; ks += 32) {
      bf16x8 af[4], bfr[4];
      #pragma unroll
      for (int i = 0; i < 4; ++i) af[i]  = READ_FRAG(sA, wm + i * 16 + lr, ks + lk);
      #pragma unroll
      for (int j = 0; j < 4; ++j) bfr[j] = READ_FRAG(sB, wn + j * 16 + lr, ks + lk);
      #pragma unroll
      for (int i = 0; i < 4; ++i)
        #pragma unroll
        for (int j = 0; j < 4; ++j)
          acc[i][j] = __builtin_amdgcn_mfma_f32_16x16x32_bf16(af[i], bfr[j], acc[i][j], 0, 0, 0);
    }
    __syncthreads();
  }
  #pragma unroll
  for (int j = 0; j < 4; ++j) {
    int col = n0 + wn + j * 16 + lr;
    float bs = bias[col];
    #pragma unroll
    for (int i = 0; i < 4; ++i) {
      int rbase = m0 + wm + i * 16 + (lane >> 4) * 4;
      #pragma unroll
      for (int e = 0; e < 4; ++e) {
        float v = acc[i][j][e] + bs;
        C[(size_t)(rbase + e) * ldc + col] = f2b(fmaxf(v, 0.0f));
      }
    }
  }
}

// ---------------- gates GEMM: 256x256 block, 8 waves, 64x128 wave tile ----------------
// R8 staging (double-buffer, issue-early STAGE, drain-late vmcnt(0)) + T3 quadrant
// phases: per K-tile 4 phases of exactly 16 MFMA; next phase's B ds_reads issue
// right after this phase's MFMAs; one pacing barrier per phase; setprio around
// each MFMA cluster (pays only with phase role-split, m218b).

#define GS_STAGE(g) do {                                                             \
    short* dA_ = &sA[((g) & 1) * 16384];                                             \
    short* dB_ = &sB[((g) & 1) * 16384];                                             \
    _Pragma("unroll")                                                                \
    for (int q_ = 0; q_ < 4; ++q_) {                                                 \
      int idx_ = q_ * 512 + t;                                                       \
      int row_ = idx_ >> 3, ds_ = idx_ & 7;                                          \
      int sc_ = (ds_ ^ (row_ & 7)) * 8;                                              \
      async_copy16(A + (size_t)(m0 + row_) * 1024 + (g) * 64 + sc_, dA_ + idx_ * 8); \
    }                                                                                \
    _Pragma("unroll")                                                                \
    for (int q_ = 0; q_ < 4; ++q_) {                                                 \
      int idx_ = q_ * 512 + t;                                                       \
      int row_ = idx_ >> 3, ds_ = idx_ & 7;                                          \
      int sc_ = (ds_ ^ (row_ & 7)) * 8;                                              \
      async_copy16(Wg + (size_t)(n0 + row_) * 1024 + (g) * 64 + sc_, dB_ + idx_ * 8);\
    }                                                                                \
  } while (0)

#define GS_LOADB(BUF, DST, NQ) do {                                                  \
    _Pragma("unroll")                                                                \
    for (int nfi_ = 0; nfi_ < 2; ++nfi_) {                                           \
      int row_ = wn * 128 + (NQ) * 32 + nfi_ * 16 + lr;                              \
      _Pragma("unroll")                                                              \
      for (int ks_ = 0; ks_ < 2; ++ks_)                                              \
        DST[nfi_][ks_] = *(const bf16x8*)&BUF[row_ * 64 + (((ks_ * 4 + hi) ^ (row_ & 7)) * 8)]; \
    }                                                                                \
  } while (0)

__global__ __launch_bounds__(512, 2)
void gates_k(const short* __restrict__ A,
             const short* __restrict__ Wg,
             const float* __restrict__ biasg,
             const short* __restrict__ c_ln,
             float* __restrict__ hbuf, float* __restrict__ cbuf)
{
  __shared__ short sA[2 * 256 * 64];   // 64 KiB
  __shared__ short sB[2 * 256 * 64];   // 64 KiB
  const int m0 = blockIdx.x * 256;
  const int n0 = blockIdx.y * 256;
  const int t = threadIdx.x;
  const int wid = t >> 6, lane = t & 63;
  const int wm = wid >> 1, wn = wid & 1;    // 4M x 2N waves, 64x128 each
  const int lr = lane & 15, hi = lane >> 4;

  f32x4 acc[4][8] = {};

  GS_STAGE(0);
  asm volatile("s_waitcnt vmcnt(0)" ::: "memory");
  __builtin_amdgcn_s_barrier();

  #pragma unroll
  for (int g = 0; g < 16; ++g) {
    const short* bA_ = &sA[(g & 1) * 16384];
    const short* bB_ = &sB[(g & 1) * 16384];
    if (g + 1 < 16) GS_STAGE(g + 1);   // into buf freed at previous tile-end barrier

    // A fragments for the whole tile (8 ds_read_b128)
    bf16x8 af_[4][2];
    #pragma unroll
    for (int mf_ = 0; mf_ < 4; ++mf_) {
      int row_ = wm * 64 + mf_ * 16 + lr;
      #pragma unroll
      for (int ks_ = 0; ks_ < 2; ++ks_)
        af_[mf_][ks_] = *(const bf16x8*)&bA_[row_ * 64 + (((ks_ * 4 + hi) ^ (row_ & 7)) * 8)];
    }
    bf16x8 b0[2][2], b1[2][2];
    GS_LOADB(bB_, b0, 0);              // quadrant 0's B (4 ds_read_b128)

    #pragma unroll
    for (int q = 0; q < 4; ++q) {
      __builtin_amdgcn_s_barrier();    // pacing barrier (T3 phase quantum)
      __builtin_amdgcn_s_setprio(1);
      #pragma unroll
      for (int mf_ = 0; mf_ < 4; ++mf_)
        #pragma unroll
        for (int nfi_ = 0; nfi_ < 2; ++nfi_) {
          if (q & 1) {
            acc[mf_][q * 2 + nfi_] = __builtin_amdgcn_mfma_f32_16x16x32_bf16(af_[mf_][0], b1[nfi_][0], acc[mf_][q * 2 + nfi_], 0, 0, 0);
            acc[mf_][q * 2 + nfi_] = __builtin_amdgcn_mfma_f32_16x16x32_bf16(af_[mf_][1], b1[nfi_][1], acc[mf_][q * 2 + nfi_], 0, 0, 0);
          } else {
            acc[mf_][q * 2 + nfi_] = __builtin_amdgcn_mfma_f32_16x16x32_bf16(af_[mf_][0], b0[nfi_][0], acc[mf_][q * 2 + nfi_], 0, 0, 0);
            acc[mf_][q * 2 + nfi_] = __builtin_amdgcn_mfma_f32_16x16x32_bf16(af_[mf_][1], b0[nfi_][1], acc[mf_][q * 2 + nfi_], 0, 0, 0);
          }
        }
      __builtin_amdgcn_s_setprio(0);
      if (q == 0) GS_LOADB(bB_, b1, 1);        // next phase's B, overlaps MFMA drain
      else if (q == 1) GS_LOADB(bB_, b0, 2);
      else if (q == 2) GS_LOADB(bB_, b1, 3);
      else if (g + 1 < 16)
        asm volatile("s_waitcnt vmcnt(0)" ::: "memory");  // drain staging issued ~1 tile ago
    }
    __builtin_amdgcn_s_barrier();      // tile boundary: staged buf now readable
  }

  // fused LSTM epilogue: nf = grp*4 + gate (gate-interleaved Wg, 64-col groups)
  #pragma unroll
  for (int grp = 0; grp < 2; ++grp) {
    const int cb = n0 + wn * 128 + grp * 64;
    const int u = ((cb >> 6)) * 16 + lr;
    const float bi_ = biasg[cb + 0 * 16 + lr];
    const float bf2 = biasg[cb + 1 * 16 + lr];
    const float bg_ = biasg[cb + 2 * 16 + lr];
    const float bo_ = biasg[cb + 3 * 16 + lr];
    #pragma unroll
    for (int mf = 0; mf < 4; ++mf) {
      int rbase = m0 + wm * 64 + mf * 16 + hi * 4;
      #pragma unroll
      for (int e = 0; e < 4; ++e) {
        int row = rbase + e;
        float iv = sigf(acc[mf][grp * 4 + 0][e] + bi_);
        float fv = sigf(acc[mf][grp * 4 + 1][e] + bf2);
        float gv = ftanh(acc[mf][grp * 4 + 2][e] + bg_);
        float ov = sigf(acc[mf][grp * 4 + 3][e] + bo_);
        float cold = b2f(c_ln[(size_t)row * 512 + u]);
        float cc = fv * cold + iv * gv;
        hbuf[(size_t)row * 512 + u] = ov * ftanh(cc);
        cbuf[(size_t)row * 512 + u] = cc;
      }
    }
  }
}

// ---------------- classifier + log_softmax over pairs ----------------
__global__ __launch_bounds__(512)
void cls_k(const float* __restrict__ hbuf, const float* __restrict__ cw,
           const float* __restrict__ cb, float* __restrict__ out)
{
  const int lane = threadIdx.x & 63;
  const int b = blockIdx.x * 8 + (threadIdx.x >> 6);
  float hl[8];
  const float* hp = hbuf + (size_t)b * 512 + lane * 8;
  *(float4*)&hl[0] = *(const float4*)hp;
  *(float4*)&hl[4] = *(const float4*)(hp + 4);
  float p[14];
  #pragma unroll
  for (int tcol = 0; tcol < 14; ++tcol) {
    const float* wr = cw + tcol * 512 + lane * 8;
    float4 w0 = *(const float4*)wr, w1 = *(const float4*)(wr + 4);
    p[tcol] = hl[0] * w0.x + hl[1] * w0.y + hl[2] * w0.z + hl[3] * w0.w
            + hl[4] * w1.x + hl[5] * w1.y + hl[6] * w1.z + hl[7] * w1.w;
  }
  #pragma unroll
  for (int o = 32; o > 0; o >>= 1)
    #pragma unroll
    for (int tcol = 0; tcol < 14; ++tcol) p[tcol] += __shfl_xor(p[tcol], o);
  if (lane < 14) {
    float z = cb[lane];
    #pragma unroll
    for (int tcol = 0; tcol < 14; ++tcol) if (lane == tcol) z += p[tcol];
    float zp = __shfl_xor(z, 1);
    float m = fmaxf(z, zp);
    float l = m + __logf(__expf(z - m) + __expf(zp - m));
    out[(size_t)b * 14 + lane] = z - l;
  }
}

// ---------------- host launch ----------------

extern "C" void kernel_launch(void* const* d_in, const int* in_sizes, int n_in,
                              void* d_out, int out_size, void* d_ws, size_t ws_size,
                              hipStream_t stream)
{
  const float* features = (const float*)d_in[0];
  const float* dec_w    = (const float*)d_in[1];
  const float* dec_b    = (const float*)d_in[2];
  const float* dec_bn_g = (const float*)d_in[3];
  const float* dec_bn_b = (const float*)d_in[4];
  const float* dec_bn_m = (const float*)d_in[5];
  const float* dec_bn_v = (const float*)d_in[6];
  const float* ea1_w    = (const float*)d_in[7];
  const float* ea1_b    = (const float*)d_in[8];
  const float* ea1_bn_g = (const float*)d_in[9];
  const float* ea1_bn_b = (const float*)d_in[10];
  const float* ea1_bn_m = (const float*)d_in[11];
  const float* ea1_bn_v = (const float*)d_in[12];
  const float* ea2_w    = (const float*)d_in[13];
  const float* ea2_b    = (const float*)d_in[14];
  const float* ea2_bn_g = (const float*)d_in[15];
  const float* ea2_bn_b = (const float*)d_in[16];
  const float* ea2_bn_m = (const float*)d_in[17];
  const float* ea2_bn_v = (const float*)d_in[18];
  const float* ei1_w    = (const float*)d_in[19];
  const float* ei1_b    = (const float*)d_in[20];
  const float* ei1_bn_g = (const float*)d_in[21];
  const float* ei1_bn_b = (const float*)d_in[22];
  const float* ei1_bn_m = (const float*)d_in[23];
  const float* ei1_bn_v = (const float*)d_in[24];
  const float* ei2_w    = (const float*)d_in[25];
  const float* ei2_b    = (const float*)d_in[26];
  const float* ei2_bn_g = (const float*)d_in[27];
  const float* ei2_bn_b = (const float*)d_in[28];
  const float* ei2_bn_m = (const float*)d_in[29];
  const float* ei2_bn_v = (const float*)d_in[30];
  const float* w_ih     = (const float*)d_in[31];
  const float* w_hh     = (const float*)d_in[32];
  const float* b_ih     = (const float*)d_in[33];
  const float* b_hh     = (const float*)d_in[34];
  const float* ln_g     = (const float*)d_in[35];
  const float* ln_b     = (const float*)d_in[36];
  const float* cls_w    = (const float*)d_in[37];
  const float* cls_b    = (const float*)d_in[38];
  (void)in_sizes; (void)n_in; (void)out_size;

  // per-row ws bytes: h 2048 + c 2048 + ghA 2048 + xa 2048 + clnb 1024 + ai 1152 = 10368
  int chunk = BSZ;
  while (chunk > 2048 && (size_t)chunk * 10368 + (16u << 20) > ws_size) chunk >>= 1;

  char* ws = (char*)d_ws;
  size_t off = 0;
  auto carve = [&](size_t bytes) -> void* {
    void* p = ws + off;
    off += (bytes + 255) & ~(size_t)255;
    return p;
  };
  short* ei1f  = (short*)carve((size_t)512 * K1P * 2);
  float* bias1 = (float*)carve(512 * 4);
  short* W2    = (short*)carve((size_t)512 * 1024 * 2);
  float* bias2 = (float*)carve(512 * 4);
  short* Wg    = (short*)carve((size_t)2048 * 1024 * 2);
  float* biasg = (float*)carve(2048 * 4);
  float* decwf = (float*)carve(7 * 512 * 4);
  float* decb8 = (float*)carve(8 * 4);
  float* ea1f  = (float*)carve(512 * 8 * 4);
  float* hbuf  = (float*)carve((size_t)chunk * 512 * 4);
  float* cbuf  = (float*)carve((size_t)chunk * 512 * 4);
  short* ghA   = (short*)carve((size_t)chunk * 1024 * 2);  // [agg | h_ln]
  short* xa    = (short*)carve((size_t)chunk * 1024 * 2);  // [x1 | a1]
  short* clnb  = (short*)carve((size_t)chunk * 512 * 2);
  short* ai    = (short*)carve((size_t)chunk * K1P * 2);

  fold_small_k<<<16, 256, 0, stream>>>(dec_w, dec_b, dec_bn_g, dec_bn_b, dec_bn_m, dec_bn_v,
                                       ea1_w, ea1_b, ea1_bn_g, ea1_bn_b, ea1_bn_m, ea1_bn_v,
                                       decwf, decb8, ea1f);
  fold_ei1_k<<<(512 * K1P) / 256, 256, 0, stream>>>(ei1_w, ei1_b, ei1_bn_g, ei1_bn_b,
                                                    ei1_bn_m, ei1_bn_v, ei1f, bias1);
  fold_w2_k<<<(512 * 1024) / 256, 256, 0, stream>>>(ei2_w, ei2_b, ei2_bn_g, ei2_bn_b, ei2_bn_m, ei2_bn_v,
                                                    ea2_w, ea2_b, ea2_bn_g, ea2_bn_b, ea2_bn_m, ea2_bn_v,
                                                    W2, bias2);
  fold_wg_k<<<(2048 * 1024) / 256, 256, 0, stream>>>(w_ih, w_hh, b_ih, b_hh, Wg, biasg);

  for (int base = 0; base < BSZ; base += chunk) {
    const float* featc = features + (size_t)base * WF;
    float* outc = (float*)d_out + (size_t)base * 14;
    for (int s = 0; s < 8; ++s) {
      attln_k<<<chunk / 8, 512, 0, stream>>>(hbuf, cbuf, decwf, decb8, ea1f, ln_g, ln_b,
                                             featc, ghA, clnb, xa, ai, (s == 0) ? 1 : 0);
      gemm_bt_k<<<(chunk / 128) * 4, 256, 0, stream>>>(ai, K1P, ei1f, K1P, bias1, xa, 1024);
      gemm_bt_k<<<(chunk / 128) * 4, 256, 0, stream>>>(xa, 1024, W2, 1024, bias2, ghA, 1024);
      gates_k<<<dim3(chunk / 256, 8), 512, 0, stream>>>(ghA, Wg, biasg, clnb, hbuf, cbuf);
    }
    cls_k<<<chunk / 8, 512, 0, stream>>>(hbuf, cls_w, cls_b, outc);
  }
}

// Round 10
// 2688.812 us; speedup vs baseline: 1.0351x; 1.0351x over previous
//
#include <hip/hip_runtime.h>
#include <cstdint>
#include <cstddef>

#define BSZ 32768
#define WN 7
#define WF 560
#define K1P 576
#define EPS 1e-5f

typedef __attribute__((ext_vector_type(8))) short bf16x8;
typedef __attribute__((ext_vector_type(4))) float f32x4;

__device__ __forceinline__ float b2f(short s) {
  union { float f; unsigned u; } x; x.u = ((unsigned)(unsigned short)s) << 16; return x.f;
}
__device__ __forceinline__ short f2b(float f) {
  union { float f; unsigned u; } x; x.f = f;
  unsigned r = x.u + 0x7fffu + ((x.u >> 16) & 1u);
  return (short)(r >> 16);
}
__device__ __forceinline__ float sigf(float x) { return 1.0f / (1.0f + __expf(-x)); }
// overflow-safe fast tanh via __expf
__device__ __forceinline__ float ftanh(float x) {
  float t = __expf(-2.0f * fabsf(x));
  float r = (1.0f - t) / (1.0f + t);
  return copysignf(r, x);
}

__device__ __forceinline__ void async_copy16(const short* g, short* l) {
  __builtin_amdgcn_global_load_lds((const __attribute__((address_space(1))) unsigned*)g,
                                   (__attribute__((address_space(3))) unsigned*)l, 16, 0, 0);
}

// ---------------- weight folding (run every call; cheap) ----------------

__global__ void fold_small_k(const float* __restrict__ dec_w, const float* __restrict__ dec_b,
                             const float* __restrict__ dec_g, const float* __restrict__ dec_bt,
                             const float* __restrict__ dec_m, const float* __restrict__ dec_v,
                             const float* __restrict__ ea1_w, const float* __restrict__ ea1_b,
                             const float* __restrict__ ea1_g, const float* __restrict__ ea1_bt,
                             const float* __restrict__ ea1_m, const float* __restrict__ ea1_v,
                             float* __restrict__ decwf, float* __restrict__ decb8,
                             float* __restrict__ ea1f)
{
  int t = blockIdx.x * 256 + threadIdx.x;
  if (t < 7 * 512) {
    int w = t >> 9;
    float s = dec_g[w] * rsqrtf(dec_v[w] + EPS);
    decwf[t] = dec_w[t] * s;
  }
  if (t < 8) {
    if (t < 7) {
      float s = dec_g[t] * rsqrtf(dec_v[t] + EPS);
      decb8[t] = (dec_b[t] - dec_m[t]) * s + dec_bt[t];
    } else decb8[t] = 0.0f;
  }
  if (t < 512) {
    float s = ea1_g[t] * rsqrtf(ea1_v[t] + EPS);
    #pragma unroll
    for (int w = 0; w < 7; ++w) ea1f[t * 8 + w] = ea1_w[t * 7 + w] * s;
    ea1f[t * 8 + 7] = (ea1_b[t] - ea1_m[t]) * s + ea1_bt[t];
  }
}

__global__ void fold_ei1_k(const float* __restrict__ w, const float* __restrict__ b,
                           const float* __restrict__ g, const float* __restrict__ bt,
                           const float* __restrict__ m, const float* __restrict__ v,
                           short* __restrict__ ei1f, float* __restrict__ bias1)
{
  int idx = blockIdx.x * 256 + threadIdx.x;   // 512*576
  int n = idx / K1P, k = idx % K1P;
  float s = g[n] * rsqrtf(v[n] + EPS);
  ei1f[idx] = (k < WF) ? f2b(w[n * WF + k] * s) : (short)0;
  if (k == 0) bias1[n] = (b[n] - m[n]) * s + bt[n];
}

__global__ void fold_w2_k(const float* __restrict__ wi, const float* __restrict__ bi,
                          const float* __restrict__ gi, const float* __restrict__ bti,
                          const float* __restrict__ mi, const float* __restrict__ vi,
                          const float* __restrict__ wa, const float* __restrict__ ba,
                          const float* __restrict__ ga, const float* __restrict__ bta,
                          const float* __restrict__ ma, const float* __restrict__ va,
                          short* __restrict__ W2, float* __restrict__ bias2)
{
  int idx = blockIdx.x * 256 + threadIdx.x;   // 512*1024
  int n = idx >> 10, k = idx & 1023;
  float si = gi[n] * rsqrtf(vi[n] + EPS);
  float sa = ga[n] * rsqrtf(va[n] + EPS);
  float val = (k < 512) ? wi[n * 512 + k] * si : wa[n * 512 + (k - 512)] * sa;
  W2[idx] = f2b(val);
  if (k == 0)
    bias2[n] = (bi[n] - mi[n]) * si + bti[n] + (ba[n] - ma[n]) * sa + bta[n];
}

// Reordered gate weights: new column c = (u>>4)*64 + g*16 + (u&15)
// so that in the MFMA epilogue, n-fragment index (mod 4) == gate, lane&15 == unit offset.
__global__ void fold_wg_k(const float* __restrict__ w_ih, const float* __restrict__ w_hh,
                          const float* __restrict__ b_ih, const float* __restrict__ b_hh,
                          short* __restrict__ Wg, float* __restrict__ biasg)
{
  int idx = blockIdx.x * 256 + threadIdx.x;   // 2048*1024
  int c = idx >> 10, k = idx & 1023;
  int g = (c >> 4) & 3;
  int u = (c >> 6) * 16 + (c & 15);
  int r = g * 512 + u;
  float val = (k < 512) ? w_ih[r * 512 + k] : w_hh[r * 512 + (k - 512)];
  Wg[idx] = f2b(val);
  if (k == 0) biasg[c] = b_ih[r] + b_hh[r];
}

// ---------------- fused attention / LN / a1 / feature-scale ----------------
__global__ __launch_bounds__(512)
void attln_k(const float* __restrict__ hbuf, const float* __restrict__ cbuf,
             const float* __restrict__ decwf, const float* __restrict__ decb8,
             const float* __restrict__ ea1f,
             const float* __restrict__ ln_g, const float* __restrict__ ln_b,
             const float* __restrict__ feat,
             short* __restrict__ ghA, short* __restrict__ c_ln,
             short* __restrict__ xa, short* __restrict__ ai, int init)
{
  const int lane = threadIdx.x & 63;
  const int b = blockIdx.x * 8 + (threadIdx.x >> 6);
  float av[WN];
  if (init) {
    const float c7 = 1.0f / 7.0f;
    #pragma unroll
    for (int w = 0; w < WN; ++w) av[w] = c7;
    int4 z = make_int4(0, 0, 0, 0);
    *(int4*)&ghA[b * 1024 + 512 + lane * 8] = z;
    *(int4*)&c_ln[b * 512 + lane * 8] = z;
  } else {
    float hl[8];
    const float* hp = hbuf + (size_t)b * 512 + lane * 8;
    *(float4*)&hl[0] = *(const float4*)hp;
    *(float4*)&hl[4] = *(const float4*)(hp + 4);
    float s = 0.f, s2 = 0.f;
    #pragma unroll
    for (int e = 0; e < 8; ++e) { s += hl[e]; s2 += hl[e] * hl[e]; }
    float p[WN];
    #pragma unroll
    for (int w = 0; w < WN; ++w) {
      const float* dw = decwf + w * 512 + lane * 8;
      float4 w0 = *(const float4*)dw, w1 = *(const float4*)(dw + 4);
      p[w] = hl[0] * w0.x + hl[1] * w0.y + hl[2] * w0.z + hl[3] * w0.w
           + hl[4] * w1.x + hl[5] * w1.y + hl[6] * w1.z + hl[7] * w1.w;
    }
    #pragma unroll
    for (int o = 32; o > 0; o >>= 1) {
      s  += __shfl_xor(s, o);
      s2 += __shfl_xor(s2, o);
      #pragma unroll
      for (int w = 0; w < WN; ++w) p[w] += __shfl_xor(p[w], o);
    }
    float mu = s * (1.0f / 512.0f);
    float var = s2 * (1.0f / 512.0f) - mu * mu;
    float rstd = rsqrtf(var + EPS);
    float ssum = 0.f;
    #pragma unroll
    for (int w = 0; w < WN; ++w) { float sg = sigf(p[w] + decb8[w]); av[w] = sg; ssum += sg; }
    float inv = 1.0f / ssum;
    #pragma unroll
    for (int w = 0; w < WN; ++w) av[w] *= inv;
    short o8[8];
    #pragma unroll
    for (int e = 0; e < 8; ++e) {
      int i = lane * 8 + e;
      o8[e] = f2b((hl[e] - mu) * rstd * ln_g[i] + ln_b[i]);
    }
    *(int4*)&ghA[b * 1024 + 512 + lane * 8] = *(int4*)o8;
    float cl[8];
    const float* cp = cbuf + (size_t)b * 512 + lane * 8;
    *(float4*)&cl[0] = *(const float4*)cp;
    *(float4*)&cl[4] = *(const float4*)(cp + 4);
    float cs = 0.f, cs2 = 0.f;
    #pragma unroll
    for (int e = 0; e < 8; ++e) { cs += cl[e]; cs2 += cl[e] * cl[e]; }
    #pragma unroll
    for (int o = 32; o > 0; o >>= 1) {
      cs  += __shfl_xor(cs, o);
      cs2 += __shfl_xor(cs2, o);
    }
    float cmu = cs * (1.0f / 512.0f);
    float cvar = cs2 * (1.0f / 512.0f) - cmu * cmu;
    float crstd = rsqrtf(cvar + EPS);
    #pragma unroll
    for (int e = 0; e < 8; ++e) {
      int i = lane * 8 + e;
      o8[e] = f2b((cl[e] - cmu) * crstd * ln_g[i] + ln_b[i]);
    }
    *(int4*)&c_ln[b * 512 + lane * 8] = *(int4*)o8;
  }
  short a8[8];
  #pragma unroll
  for (int e = 0; e < 8; ++e) {
    int n = lane * 8 + e;
    const float* wr = ea1f + n * 8;
    float4 w0 = *(const float4*)wr, w1 = *(const float4*)(wr + 4);
    float v = w1.w
            + av[0] * w0.x + av[1] * w0.y + av[2] * w0.z + av[3] * w0.w
            + av[4] * w1.x + av[5] * w1.y + av[6] * w1.z;
    a8[e] = f2b(fmaxf(v, 0.0f));
  }
  *(int4*)&xa[b * 1024 + 512 + lane * 8] = *(int4*)a8;
  const float* fr = feat + (size_t)b * WF;
  short* air = ai + (size_t)b * K1P;
  #pragma unroll
  for (int rr = 0; rr < 2; ++rr) {
    int c8 = lane + rr * 64;
    if (c8 < 72) {
      int k = c8 * 8;
      short s8[8];
      if (k < WF) {
        int window = c8 / 10;
        float a = av[0];
        #pragma unroll
        for (int w = 1; w < WN; ++w) a = (window == w) ? av[w] : a;
        float4 f0 = *(const float4*)(fr + k);
        float4 f1 = *(const float4*)(fr + k + 4);
        s8[0] = f2b(f0.x * a); s8[1] = f2b(f0.y * a); s8[2] = f2b(f0.z * a); s8[3] = f2b(f0.w * a);
        s8[4] = f2b(f1.x * a); s8[5] = f2b(f1.y * a); s8[6] = f2b(f1.z * a); s8[7] = f2b(f1.w * a);
      } else {
        #pragma unroll
        for (int e = 0; e < 8; ++e) s8[e] = 0;
      }
      *(int4*)&air[k] = *(int4*)s8;
    }
  }
}

// ---------------- encoder GEMM: 128x128 tile, double-buffered, issue-early ----------------
// LDS 64 KiB -> 2 blocks/CU (cross-block overlap hides the per-tile drain).
// STAGE(g+1) issued before COMPUTE(g); one vmcnt(0)+s_barrier per K-tile.
// Race-free: stage targets buf (g+1)&1 whose readers retired before the barrier
// ending tile g-1; per-wave ds_read->MFMA order enforced by compiler lgkm waits.

#define E_STAGE(g) do {                                                              \
    short* dA_ = &sA[((g) & 1) * 8192];                                              \
    short* dB_ = &sB[((g) & 1) * 8192];                                              \
    _Pragma("unroll")                                                                \
    for (int q_ = 0; q_ < 4; ++q_) {                                                 \
      int idx_ = q_ * 256 + t;                                                       \
      int row_ = idx_ >> 3, dcol_ = (idx_ & 7) * 8;                                  \
      int scol_ = dcol_ ^ ((row_ & 7) << 3);                                         \
      async_copy16(Ab + (size_t)row_ * lda + (g) * 64 + scol_, dA_ + idx_ * 8);      \
    }                                                                                \
    _Pragma("unroll")                                                                \
    for (int q_ = 0; q_ < 4; ++q_) {                                                 \
      int idx_ = q_ * 256 + t;                                                       \
      int row_ = idx_ >> 3, dcol_ = (idx_ & 7) * 8;                                  \
      int scol_ = dcol_ ^ ((row_ & 7) << 3);                                         \
      async_copy16(Wb + (size_t)row_ * K + (g) * 64 + scol_, dB_ + idx_ * 8);        \
    }                                                                                \
  } while (0)

#define READ_FRAGB(BASE, ROW, KS) \
  (*(const bf16x8*)&BASE[(ROW) * 64 + (((KS)) ^ (((ROW) & 7) << 3))])

template<int KT>   // number of 64-wide K tiles (9 for K=576, 16 for K=1024)
__global__ __launch_bounds__(256)
void gemm_bt_k(const short* __restrict__ A, int lda,
               const short* __restrict__ Wt, int K,
               const float* __restrict__ bias,
               short* __restrict__ C, int ldc)
{
  const int bswz = blockIdx.x;
  const int xcd = bswz & 7, slot = bswz >> 3;
  const int m0 = (xcd + 8 * (slot >> 2)) * 128;
  const int n0 = (slot & 3) * 128;
  __shared__ short sA[2 * 128 * 64];
  __shared__ short sB[2 * 128 * 64];
  const int t = threadIdx.x;
  const int wv = t >> 6, lane = t & 63;
  const int wm = (wv & 1) * 64, wn = (wv >> 1) * 64;
  const int lr = lane & 15, lk = (lane >> 4) * 8;

  f32x4 acc[4][4] = {};
  const short* Ab = A + (size_t)m0 * lda;
  const short* Wb = Wt + (size_t)n0 * K;

  E_STAGE(0);
  asm volatile("s_waitcnt vmcnt(0)" ::: "memory");
  __builtin_amdgcn_s_barrier();

  #pragma unroll
  for (int g = 0; g < KT; ++g) {
    const short* bA_ = &sA[(g & 1) * 8192];
    const short* bB_ = &sB[(g & 1) * 8192];
    if (g + 1 < KT) E_STAGE(g + 1);
    #pragma unroll
    for (int ks = 0; ks < 64; ks += 32) {
      bf16x8 af[4], bfr[4];
      #pragma unroll
      for (int i = 0; i < 4; ++i) af[i]  = READ_FRAGB(bA_, wm + i * 16 + lr, ks + lk);
      #pragma unroll
      for (int j = 0; j < 4; ++j) bfr[j] = READ_FRAGB(bB_, wn + j * 16 + lr, ks + lk);
      #pragma unroll
      for (int i = 0; i < 4; ++i)
        #pragma unroll
        for (int j = 0; j < 4; ++j)
          acc[i][j] = __builtin_amdgcn_mfma_f32_16x16x32_bf16(af[i], bfr[j], acc[i][j], 0, 0, 0);
    }
    if (g + 1 < KT) {
      asm volatile("s_waitcnt vmcnt(0)" ::: "memory");
      __builtin_amdgcn_s_barrier();
    }
  }
  #pragma unroll
  for (int j = 0; j < 4; ++j) {
    int col = n0 + wn + j * 16 + lr;
    float bs = bias[col];
    #pragma unroll
    for (int i = 0; i < 4; ++i) {
      int rbase = m0 + wm + i * 16 + (lane >> 4) * 4;
      #pragma unroll
      for (int e = 0; e < 4; ++e) {
        float v = acc[i][j][e] + bs;
        C[(size_t)(rbase + e) * ldc + col] = f2b(fmaxf(v, 0.0f));
      }
    }
  }
}

// ---------------- gates GEMM: 256x256 block, 8 waves, 64x128 wave tile (R8) ----------------
// Double-buffered BK=64 (128 KiB LDS), issue-early/drain-late: STAGE(g+1) issued
// BEFORE COMPUTE(g), vmcnt(0) drained after -> wait mostly hidden; ONE barrier/K-tile.

#define GS_STAGE(g) do {                                                             \
    short* dA_ = &sA[((g) & 1) * 16384];                                             \
    short* dB_ = &sB[((g) & 1) * 16384];                                             \
    _Pragma("unroll")                                                                \
    for (int q_ = 0; q_ < 4; ++q_) {                                                 \
      int idx_ = q_ * 512 + t;                                                       \
      int row_ = idx_ >> 3, ds_ = idx_ & 7;                                          \
      int sc_ = (ds_ ^ (row_ & 7)) * 8;                                              \
      async_copy16(A + (size_t)(m0 + row_) * 1024 + (g) * 64 + sc_, dA_ + idx_ * 8); \
    }                                                                                \
    _Pragma("unroll")                                                                \
    for (int q_ = 0; q_ < 4; ++q_) {                                                 \
      int idx_ = q_ * 512 + t;                                                       \
      int row_ = idx_ >> 3, ds_ = idx_ & 7;                                          \
      int sc_ = (ds_ ^ (row_ & 7)) * 8;                                              \
      async_copy16(Wg + (size_t)(n0 + row_) * 1024 + (g) * 64 + sc_, dB_ + idx_ * 8);\
    }                                                                                \
  } while (0)

#define GS_COMPUTE(g) do {                                                           \
    const short* bA_ = &sA[((g) & 1) * 16384];                                       \
    const short* bB_ = &sB[((g) & 1) * 16384];                                       \
    _Pragma("unroll")                                                                \
    for (int ks_ = 0; ks_ < 2; ++ks_) {                                              \
      bf16x8 af_[4], bf_[8];                                                         \
      _Pragma("unroll")                                                              \
      for (int mf_ = 0; mf_ < 4; ++mf_) {                                            \
        int row_ = wm * 64 + mf_ * 16 + lr;                                          \
        af_[mf_] = *(const bf16x8*)&bA_[row_ * 64 + (((ks_ * 4 + hi) ^ (row_ & 7)) * 8)]; \
      }                                                                              \
      _Pragma("unroll")                                                              \
      for (int nf_ = 0; nf_ < 8; ++nf_) {                                            \
        int row_ = wn * 128 + nf_ * 16 + lr;                                         \
        bf_[nf_] = *(const bf16x8*)&bB_[row_ * 64 + (((ks_ * 4 + hi) ^ (row_ & 7)) * 8)]; \
      }                                                                              \
      __builtin_amdgcn_s_setprio(1);                                                 \
      _Pragma("unroll")                                                              \
      for (int mf_ = 0; mf_ < 4; ++mf_)                                              \
        _Pragma("unroll")                                                            \
        for (int nf_ = 0; nf_ < 8; ++nf_)                                            \
          acc[mf_][nf_] = __builtin_amdgcn_mfma_f32_16x16x32_bf16(af_[mf_], bf_[nf_], acc[mf_][nf_], 0, 0, 0); \
      __builtin_amdgcn_s_setprio(0);                                                 \
    }                                                                                \
  } while (0)

__global__ __launch_bounds__(512, 2)
void gates_k(const short* __restrict__ A,
             const short* __restrict__ Wg,
             const float* __restrict__ biasg,
             const short* __restrict__ c_ln,
             float* __restrict__ hbuf, float* __restrict__ cbuf)
{
  __shared__ short sA[2 * 256 * 64];   // 64 KiB
  __shared__ short sB[2 * 256 * 64];   // 64 KiB
  const int m0 = blockIdx.x * 256;
  const int n0 = blockIdx.y * 256;
  const int t = threadIdx.x;
  const int wid = t >> 6, lane = t & 63;
  const int wm = wid >> 1, wn = wid & 1;    // 4M x 2N waves, 64x128 each
  const int lr = lane & 15, hi = lane >> 4;

  f32x4 acc[4][8] = {};

  GS_STAGE(0);
  asm volatile("s_waitcnt vmcnt(0)" ::: "memory");
  __builtin_amdgcn_s_barrier();

  #pragma unroll
  for (int g = 0; g < 16; ++g) {
    if (g + 1 < 16) GS_STAGE(g + 1);          // issue-early into buf freed last barrier
    GS_COMPUTE(g);
    if (g + 1 < 16) {
      asm volatile("s_waitcnt vmcnt(0) lgkmcnt(0)" ::: "memory");  // drain-late
      __builtin_amdgcn_s_barrier();
    }
  }

  // fused LSTM epilogue: nf = grp*4 + gate (gate-interleaved Wg, 64-col groups)
  #pragma unroll
  for (int grp = 0; grp < 2; ++grp) {
    const int cb = n0 + wn * 128 + grp * 64;
    const int u = ((cb >> 6)) * 16 + lr;
    const float bi_ = biasg[cb + 0 * 16 + lr];
    const float bf2 = biasg[cb + 1 * 16 + lr];
    const float bg_ = biasg[cb + 2 * 16 + lr];
    const float bo_ = biasg[cb + 3 * 16 + lr];
    #pragma unroll
    for (int mf = 0; mf < 4; ++mf) {
      int rbase = m0 + wm * 64 + mf * 16 + hi * 4;
      #pragma unroll
      for (int e = 0; e < 4; ++e) {
        int row = rbase + e;
        float iv = sigf(acc[mf][grp * 4 + 0][e] + bi_);
        float fv = sigf(acc[mf][grp * 4 + 1][e] + bf2);
        float gv = ftanh(acc[mf][grp * 4 + 2][e] + bg_);
        float ov = sigf(acc[mf][grp * 4 + 3][e] + bo_);
        float cold = b2f(c_ln[(size_t)row * 512 + u]);
        float cc = fv * cold + iv * gv;
        hbuf[(size_t)row * 512 + u] = ov * ftanh(cc);
        cbuf[(size_t)row * 512 + u] = cc;
      }
    }
  }
}

// ---------------- classifier + log_softmax over pairs ----------------
__global__ __launch_bounds__(512)
void cls_k(const float* __restrict__ hbuf, const float* __restrict__ cw,
           const float* __restrict__ cb, float* __restrict__ out)
{
  const int lane = threadIdx.x & 63;
  const int b = blockIdx.x * 8 + (threadIdx.x >> 6);
  float hl[8];
  const float* hp = hbuf + (size_t)b * 512 + lane * 8;
  *(float4*)&hl[0] = *(const float4*)hp;
  *(float4*)&hl[4] = *(const float4*)(hp + 4);
  float p[14];
  #pragma unroll
  for (int tcol = 0; tcol < 14; ++tcol) {
    const float* wr = cw + tcol * 512 + lane * 8;
    float4 w0 = *(const float4*)wr, w1 = *(const float4*)(wr + 4);
    p[tcol] = hl[0] * w0.x + hl[1] * w0.y + hl[2] * w0.z + hl[3] * w0.w
            + hl[4] * w1.x + hl[5] * w1.y + hl[6] * w1.z + hl[7] * w1.w;
  }
  #pragma unroll
  for (int o = 32; o > 0; o >>= 1)
    #pragma unroll
    for (int tcol = 0; tcol < 14; ++tcol) p[tcol] += __shfl_xor(p[tcol], o);
  if (lane < 14) {
    float z = cb[lane];
    #pragma unroll
    for (int tcol = 0; tcol < 14; ++tcol) if (lane == tcol) z += p[tcol];
    float zp = __shfl_xor(z, 1);
    float m = fmaxf(z, zp);
    float l = m + __logf(__expf(z - m) + __expf(zp - m));
    out[(size_t)b * 14 + lane] = z - l;
  }
}

// ---------------- host launch ----------------

extern "C" void kernel_launch(void* const* d_in, const int* in_sizes, int n_in,
                              void* d_out, int out_size, void* d_ws, size_t ws_size,
                              hipStream_t stream)
{
  const float* features = (const float*)d_in[0];
  const float* dec_w    = (const float*)d_in[1];
  const float* dec_b    = (const float*)d_in[2];
  const float* dec_bn_g = (const float*)d_in[3];
  const float* dec_bn_b = (const float*)d_in[4];
  const float* dec_bn_m = (const float*)d_in[5];
  const float* dec_bn_v = (const float*)d_in[6];
  const float* ea1_w    = (const float*)d_in[7];
  const float* ea1_b    = (const float*)d_in[8];
  const float* ea1_bn_g = (const float*)d_in[9];
  const float* ea1_bn_b = (const float*)d_in[10];
  const float* ea1_bn_m = (const float*)d_in[11];
  const float* ea1_bn_v = (const float*)d_in[12];
  const float* ea2_w    = (const float*)d_in[13];
  const float* ea2_b    = (const float*)d_in[14];
  const float* ea2_bn_g = (const float*)d_in[15];
  const float* ea2_bn_b = (const float*)d_in[16];
  const float* ea2_bn_m = (const float*)d_in[17];
  const float* ea2_bn_v = (const float*)d_in[18];
  const float* ei1_w    = (const float*)d_in[19];
  const float* ei1_b    = (const float*)d_in[20];
  const float* ei1_bn_g = (const float*)d_in[21];
  const float* ei1_bn_b = (const float*)d_in[22];
  const float* ei1_bn_m = (const float*)d_in[23];
  const float* ei1_bn_v = (const float*)d_in[24];
  const float* ei2_w    = (const float*)d_in[25];
  const float* ei2_b    = (const float*)d_in[26];
  const float* ei2_bn_g = (const float*)d_in[27];
  const float* ei2_bn_b = (const float*)d_in[28];
  const float* ei2_bn_m = (const float*)d_in[29];
  const float* ei2_bn_v = (const float*)d_in[30];
  const float* w_ih     = (const float*)d_in[31];
  const float* w_hh     = (const float*)d_in[32];
  const float* b_ih     = (const float*)d_in[33];
  const float* b_hh     = (const float*)d_in[34];
  const float* ln_g     = (const float*)d_in[35];
  const float* ln_b     = (const float*)d_in[36];
  const float* cls_w    = (const float*)d_in[37];
  const float* cls_b    = (const float*)d_in[38];
  (void)in_sizes; (void)n_in; (void)out_size;

  // per-row ws bytes: h 2048 + c 2048 + ghA 2048 + xa 2048 + clnb 1024 + ai 1152 = 10368
  int chunk = BSZ;
  while (chunk > 2048 && (size_t)chunk * 10368 + (16u << 20) > ws_size) chunk >>= 1;

  char* ws = (char*)d_ws;
  size_t off = 0;
  auto carve = [&](size_t bytes) -> void* {
    void* p = ws + off;
    off += (bytes + 255) & ~(size_t)255;
    return p;
  };
  short* ei1f  = (short*)carve((size_t)512 * K1P * 2);
  float* bias1 = (float*)carve(512 * 4);
  short* W2    = (short*)carve((size_t)512 * 1024 * 2);
  float* bias2 = (float*)carve(512 * 4);
  short* Wg    = (short*)carve((size_t)2048 * 1024 * 2);
  float* biasg = (float*)carve(2048 * 4);
  float* decwf = (float*)carve(7 * 512 * 4);
  float* decb8 = (float*)carve(8 * 4);
  float* ea1f  = (float*)carve(512 * 8 * 4);
  float* hbuf  = (float*)carve((size_t)chunk * 512 * 4);
  float* cbuf  = (float*)carve((size_t)chunk * 512 * 4);
  short* ghA   = (short*)carve((size_t)chunk * 1024 * 2);  // [agg | h_ln]
  short* xa    = (short*)carve((size_t)chunk * 1024 * 2);  // [x1 | a1]
  short* clnb  = (short*)carve((size_t)chunk * 512 * 2);
  short* ai    = (short*)carve((size_t)chunk * K1P * 2);

  fold_small_k<<<16, 256, 0, stream>>>(dec_w, dec_b, dec_bn_g, dec_bn_b, dec_bn_m, dec_bn_v,
                                       ea1_w, ea1_b, ea1_bn_g, ea1_bn_b, ea1_bn_m, ea1_bn_v,
                                       decwf, decb8, ea1f);
  fold_ei1_k<<<(512 * K1P) / 256, 256, 0, stream>>>(ei1_w, ei1_b, ei1_bn_g, ei1_bn_b,
                                                    ei1_bn_m, ei1_bn_v, ei1f, bias1);
  fold_w2_k<<<(512 * 1024) / 256, 256, 0, stream>>>(ei2_w, ei2_b, ei2_bn_g, ei2_bn_b, ei2_bn_m, ei2_bn_v,
                                                    ea2_w, ea2_b, ea2_bn_g, ea2_bn_b, ea2_bn_m, ea2_bn_v,
                                                    W2, bias2);
  fold_wg_k<<<(2048 * 1024) / 256, 256, 0, stream>>>(w_ih, w_hh, b_ih, b_hh, Wg, biasg);

  for (int base = 0; base < BSZ; base += chunk) {
    const float* featc = features + (size_t)base * WF;
    float* outc = (float*)d_out + (size_t)base * 14;
    for (int s = 0; s < 8; ++s) {
      attln_k<<<chunk / 8, 512, 0, stream>>>(hbuf, cbuf, decwf, decb8, ea1f, ln_g, ln_b,
                                             featc, ghA, clnb, xa, ai, (s == 0) ? 1 : 0);
      gemm_bt_k<9><<<(chunk / 128) * 4, 256, 0, stream>>>(ai, K1P, ei1f, K1P, bias1, xa, 1024);
      gemm_bt_k<16><<<(chunk / 128) * 4, 256, 0, stream>>>(xa, 1024, W2, 1024, bias2, ghA, 1024);
      gates_k<<<dim3(chunk / 256, 8), 512, 0, stream>>>(ghA, Wg, biasg, clnb, hbuf, cbuf);
    }
    cls_k<<<chunk / 8, 512, 0, stream>>>(hbuf, cls_w, cls_b, outc);
  }
}